// Round 8
// baseline (75.114 us; speedup 1.0000x reference)
//
#include <hip/hip_runtime.h>
#include <hip/hip_bf16.h>

#define D_NODE 80
#define EDGE_ITERS 2   // 32-edge tiles per wave; all gathers issued upfront

typedef __attribute__((ext_vector_type(8))) short short8;
typedef __attribute__((ext_vector_type(16))) float f32x16;
typedef __attribute__((ext_vector_type(4))) float f32x4v;
typedef __attribute__((ext_vector_type(2))) float f32x2v;

__device__ __forceinline__ float bf16lo(unsigned u) {
    return __uint_as_float(u << 16);
}
__device__ __forceinline__ float bf16hi(unsigned u) {
    return __uint_as_float(u & 0xffff0000u);
}
__device__ __forceinline__ unsigned packbf2(float a, float b) {
    __hip_bfloat162 h = __float22bfloat162_rn(make_float2(a, b));
    union { __hip_bfloat162 h2; unsigned u; } cv; cv.h2 = h;
    return cv.u;   // low 16 bits = a, high = b
}
__device__ __forceinline__ short f2bf(float f) {
    __hip_bfloat16 h = __float2bfloat16(f);
    union { __hip_bfloat16 h1; short s; } cv; cv.h1 = h;
    return cv.s;
}
__device__ __forceinline__ float4 nt_load_f4(const float* p) {
    f32x4v v = __builtin_nontemporal_load((const f32x4v*)p);
    return make_float4(v[0], v[1], v[2], v[3]);
}

// Kernel 1: per-node projection as MFMA GEMM, grid-stride with X prefetch-1.
// A = W1 columns (feats on M, VGPR-resident), B = X tile (32 nodes on N),
// K=80 in 5 steps. cs -> PS ; cd (+ b1 + W1[80] folded) -> PD.
// X loads nontemporal (read-once stream, keep L2 for the tables).
__global__ __launch_bounds__(256) void proj_kernel(
    const float* __restrict__ X, const float* __restrict__ W1,
    const float* __restrict__ b1,
    unsigned short* __restrict__ PS, unsigned short* __restrict__ PD, int N)
{
    const int lane = threadIdx.x & 63;
    const int wave = threadIdx.x >> 6;
    const int n    = lane & 31;   // node-in-tile (B/C col) ; feat (A row) for W loads
    const int hi   = lane >> 5;   // k-slot group

    const int tiles  = N / 32;            // 3125 for N=100000
    const int stride = gridDim.x * 4;
    int tile = blockIdx.x * 4 + wave;
    if (tile >= tiles) return;

    // first tile's X loads issued BEFORE the W-fragment setup (both in flight)
    float4 xc[10];
    {
        const float* xrow = X + (size_t)(tile * 32 + n) * D_NODE + hi * 8;
#pragma unroll
        for (int s = 0; s < 5; ++s) {
            xc[2*s]   = nt_load_f4(xrow + s * 16);
            xc[2*s+1] = nt_load_f4(xrow + s * 16 + 4);
        }
    }

    // W fragments, loaded once per wave (coalesced: lanes 0..31 read a 128B row)
    short8 Ws[5], Wd[5];
#pragma unroll
    for (int s = 0; s < 5; ++s) {
#pragma unroll
        for (int j = 0; j < 8; ++j) {
            int k = s * 16 + hi * 8 + j;
            Ws[s][j] = f2bf(W1[k * 32 + n]);
            Wd[s][j] = f2bf(W1[(81 + k) * 32 + n]);
        }
    }
    // C-init for PD: b1[feat] + W1[80][feat]
    float cdInit[16];
#pragma unroll
    for (int r = 0; r < 16; ++r) {
        int f = (r & 3) + 8 * (r >> 2) + 4 * hi;
        cdInit[r] = b1[f] + W1[80 * 32 + f];
    }

    while (tile < tiles) {
        const int nt = tile + stride;
        float4 xn[10];
        if (nt < tiles) {   // prefetch next tile's X under this tile's compute
            const float* xrow = X + (size_t)(nt * 32 + n) * D_NODE + hi * 8;
#pragma unroll
            for (int s = 0; s < 5; ++s) {
                xn[2*s]   = nt_load_f4(xrow + s * 16);
                xn[2*s+1] = nt_load_f4(xrow + s * 16 + 4);
            }
        }

        f32x16 cs, cd;
#pragma unroll
        for (int r = 0; r < 16; ++r) { cs[r] = 0.0f; cd[r] = cdInit[r]; }

#pragma unroll
        for (int s = 0; s < 5; ++s) {
            union { uint4 u; short8 s8; } Bx;
            Bx.u.x = packbf2(xc[2*s].x, xc[2*s].y);
            Bx.u.y = packbf2(xc[2*s].z, xc[2*s].w);
            Bx.u.z = packbf2(xc[2*s+1].x, xc[2*s+1].y);
            Bx.u.w = packbf2(xc[2*s+1].z, xc[2*s+1].w);
            cs = __builtin_amdgcn_mfma_f32_32x32x16_bf16(Ws[s], Bx.s8, cs, 0, 0, 0);
            cd = __builtin_amdgcn_mfma_f32_32x32x16_bf16(Wd[s], Bx.s8, cd, 0, 0, 0);
        }

        const int node = tile * 32 + n;
        unsigned short* psr = PS + (size_t)node * 32 + hi * 4;
        unsigned short* pdr = PD + (size_t)node * 32 + hi * 4;
#pragma unroll
        for (int q = 0; q < 4; ++q) {
            uint2 vs = make_uint2(packbf2(cs[4*q+0], cs[4*q+1]),
                                  packbf2(cs[4*q+2], cs[4*q+3]));
            uint2 vd = make_uint2(packbf2(cd[4*q+0], cd[4*q+1]),
                                  packbf2(cd[4*q+2], cd[4*q+3]));
            *(uint2*)(psr + q * 8) = vs;
            *(uint2*)(pdr + q * 8) = vd;
        }

#pragma unroll
        for (int i = 0; i < 10; ++i) xc[i] = xn[i];
        tile = nt;
    }
}

// Kernel 2: 32 edges per wave-iteration via mfma_f32_32x32x16_bf16.
// A = W2 (feats on M), B = h1 tile (32 edges on N), 2 k-steps.
// 512-thread blocks (8 waves) for residency; ei nontemporal (read-once),
// out nontemporal store (never re-read); PS/PD cached (the hot tables).
__global__ __launch_bounds__(512) void edge_kernel(
    const int* __restrict__ ei,
    const unsigned short* __restrict__ PS, const unsigned short* __restrict__ PD,
    const float* __restrict__ W2, const float* __restrict__ b2,
    const float* __restrict__ W3, const float* __restrict__ b3,
    float* __restrict__ out, int E)
{
    const int tid  = threadIdx.x;
    const int wave = tid >> 6;
    const int lane = tid & 63;
    const int n    = lane & 31;   // edge-in-tile (B col / C col)
    const int hi   = lane >> 5;   // k-slot group

    // A fragments: step t, slot j <-> k = t*16 + hi*8 + j; A[m=n][k] = W2[k][m]
    short8 Wa0, Wa1;
#pragma unroll
    for (int j = 0; j < 8; ++j) {
        int k0 = hi * 8 + j;
        Wa0[j] = f2bf(W2[k0 * 32 + n]);
        Wa1[j] = f2bf(W2[(16 + k0) * 32 + n]);
    }
    // per-lane constants for the 16 C-rows this lane owns (packed bf16 pairs)
    unsigned b2p[8], w3p[16];
#pragma unroll
    for (int r = 0; r < 16; ++r) {
        int row = (r & 3) + 8 * (r >> 2) + 4 * hi;
        w3p[r] = packbf2(W3[row * 2 + 0], W3[row * 2 + 1]);
        if ((r & 1) == 0) {
            int row2 = ((r + 1) & 3) + 8 * ((r + 1) >> 2) + 4 * hi;
            b2p[r >> 1] = packbf2(b2[row], b2[row2]);
        }
    }
    const float b30 = b3[0], b31 = b3[1];

    const long base = ((long)blockIdx.x * 8 + wave) * (32 * EDGE_ITERS);

    // index loads: all in flight immediately (nontemporal read-once stream)
    int sIdx[EDGE_ITERS], dIdx[EDGE_ITERS];
#pragma unroll
    for (int it = 0; it < EDGE_ITERS; ++it) {
        long e = base + (long)it * 32 + n;
        int ec = (e < E) ? (int)e : 0;
        sIdx[it] = __builtin_nontemporal_load(ei + ec);
        dIdx[it] = __builtin_nontemporal_load(ei + (size_t)E + ec);
    }

    // row gathers for BOTH tiles issued upfront (8 x 16B in flight per lane)
    uint4 av0[EDGE_ITERS], av1[EDGE_ITERS], bv0[EDGE_ITERS], bv1[EDGE_ITERS];
#pragma unroll
    for (int it = 0; it < EDGE_ITERS; ++it) {
        av0[it] = *(const uint4*)(PS + (size_t)sIdx[it] * 32 + hi * 8);
        av1[it] = *(const uint4*)(PS + (size_t)sIdx[it] * 32 + 16 + hi * 8);
        bv0[it] = *(const uint4*)(PD + (size_t)dIdx[it] * 32 + hi * 8);
        bv1[it] = *(const uint4*)(PD + (size_t)dIdx[it] * 32 + 16 + hi * 8);
    }

#pragma unroll
    for (int it = 0; it < EDGE_ITERS; ++it) {
        union { uint4 u; short8 s8; } B0, B1;
        B0.u.x = packbf2(fmaxf(bf16lo(av0[it].x) + bf16lo(bv0[it].x), 0.f),
                         fmaxf(bf16hi(av0[it].x) + bf16hi(bv0[it].x), 0.f));
        B0.u.y = packbf2(fmaxf(bf16lo(av0[it].y) + bf16lo(bv0[it].y), 0.f),
                         fmaxf(bf16hi(av0[it].y) + bf16hi(bv0[it].y), 0.f));
        B0.u.z = packbf2(fmaxf(bf16lo(av0[it].z) + bf16lo(bv0[it].z), 0.f),
                         fmaxf(bf16hi(av0[it].z) + bf16hi(bv0[it].z), 0.f));
        B0.u.w = packbf2(fmaxf(bf16lo(av0[it].w) + bf16lo(bv0[it].w), 0.f),
                         fmaxf(bf16hi(av0[it].w) + bf16hi(bv0[it].w), 0.f));
        B1.u.x = packbf2(fmaxf(bf16lo(av1[it].x) + bf16lo(bv1[it].x), 0.f),
                         fmaxf(bf16hi(av1[it].x) + bf16hi(bv1[it].x), 0.f));
        B1.u.y = packbf2(fmaxf(bf16lo(av1[it].y) + bf16lo(bv1[it].y), 0.f),
                         fmaxf(bf16hi(av1[it].y) + bf16hi(bv1[it].y), 0.f));
        B1.u.z = packbf2(fmaxf(bf16lo(av1[it].z) + bf16lo(bv1[it].z), 0.f),
                         fmaxf(bf16hi(av1[it].z) + bf16hi(bv1[it].z), 0.f));
        B1.u.w = packbf2(fmaxf(bf16lo(av1[it].w) + bf16lo(bv1[it].w), 0.f),
                         fmaxf(bf16hi(av1[it].w) + bf16hi(bv1[it].w), 0.f));

        f32x16 c;
#pragma unroll
        for (int q = 0; q < 8; ++q) {
            c[2*q]   = bf16lo(b2p[q]);
            c[2*q+1] = bf16hi(b2p[q]);
        }
        c = __builtin_amdgcn_mfma_f32_32x32x16_bf16(Wa0, B0.s8, c, 0, 0, 0);
        c = __builtin_amdgcn_mfma_f32_32x32x16_bf16(Wa1, B1.s8, c, 0, 0, 0);

        float p0 = 0.f, p1 = 0.f;
#pragma unroll
        for (int r = 0; r < 16; ++r) {
            float h = fmaxf(c[r], 0.f);
            p0 += h * bf16lo(w3p[r]);
            p1 += h * bf16hi(w3p[r]);
        }
        p0 += __shfl_xor(p0, 32, 64);
        p1 += __shfl_xor(p1, 32, 64);

        if (hi == 0) {
            long eo = base + (long)it * 32 + n;
            if (eo < E) {
                float l0 = p0 + b30;
                float l1 = p1 + b31;
                float mm = fmaxf(l0, l1);
                float z  = __expf(l0 - mm) + __expf(l1 - mm);
                float lse = mm + __logf(z);
                f32x2v o; o[0] = l0 - lse; o[1] = l1 - lse;
                __builtin_nontemporal_store(o, (f32x2v*)(out + 2 * eo));
            }
        }
    }
}

extern "C" void kernel_launch(void* const* d_in, const int* in_sizes, int n_in,
                              void* d_out, int out_size, void* d_ws, size_t ws_size,
                              hipStream_t stream) {
    const float* X  = (const float*)d_in[0];
    const int*   ei = (const int*)d_in[1];
    const float* W1 = (const float*)d_in[2];
    const float* b1 = (const float*)d_in[3];
    const float* W2 = (const float*)d_in[4];
    const float* b2 = (const float*)d_in[5];
    const float* W3 = (const float*)d_in[6];
    const float* b3 = (const float*)d_in[7];
    float* out = (float*)d_out;

    int N = in_sizes[0] / D_NODE;   // 100000
    int E = in_sizes[1] / 2;        // 1600000

    unsigned short* PS = (unsigned short*)d_ws;            // N*32 bf16 = 6.4 MB
    unsigned short* PD = PS + (size_t)N * 32;              // N*32 bf16 = 6.4 MB

    proj_kernel<<<391, 256, 0, stream>>>(X, W1, b1, PS, PD, N);   // ~2 tiles/wave

    int edges_per_block = 8 * 32 * EDGE_ITERS;             // 512
    int nblk = (E + edges_per_block - 1) / edges_per_block; // 3125
    edge_kernel<<<nblk, 512, 0, stream>>>(ei, PS, PD, W2, b2, W3, b3, out, E);
}

// Round 9
// 64.310 us; speedup vs baseline: 1.1680x; 1.1680x over previous
//
#include <hip/hip_runtime.h>
#include <hip/hip_bf16.h>

#define D_NODE 80
#define EDGE_ITERS 4   // 32-edge tiles per wave; gathers pinned in flight

typedef __attribute__((ext_vector_type(8))) short short8;
typedef __attribute__((ext_vector_type(16))) float f32x16;

__device__ __forceinline__ float bf16lo(unsigned u) {
    return __uint_as_float(u << 16);
}
__device__ __forceinline__ float bf16hi(unsigned u) {
    return __uint_as_float(u & 0xffff0000u);
}
__device__ __forceinline__ unsigned packbf2(float a, float b) {
    __hip_bfloat162 h = __float22bfloat162_rn(make_float2(a, b));
    union { __hip_bfloat162 h2; unsigned u; } cv; cv.h2 = h;
    return cv.u;   // low 16 bits = a, high = b
}
__device__ __forceinline__ short f2bf(float f) {
    __hip_bfloat16 h = __float2bfloat16(f);
    union { __hip_bfloat16 h1; short s; } cv; cv.h1 = h;
    return cv.s;
}

// Kernel 1: per-node projection as MFMA GEMM, grid-stride with X prefetch-1.
// (byte-identical to round-7's proj — its best measured config, ~15 µs)
__global__ __launch_bounds__(256) void proj_kernel(
    const float* __restrict__ X, const float* __restrict__ W1,
    const float* __restrict__ b1,
    unsigned short* __restrict__ PS, unsigned short* __restrict__ PD, int N)
{
    const int lane = threadIdx.x & 63;
    const int wave = threadIdx.x >> 6;
    const int n    = lane & 31;   // node-in-tile (B/C col) ; feat (A row) for W loads
    const int hi   = lane >> 5;   // k-slot group

    const int tiles  = N / 32;            // 3125 for N=100000
    const int stride = gridDim.x * 4;
    int tile = blockIdx.x * 4 + wave;
    if (tile >= tiles) return;

    // first tile's X loads issued BEFORE the W-fragment setup (both in flight)
    float4 xc[10];
    {
        const float4* xrow = (const float4*)(X + (size_t)(tile * 32 + n) * D_NODE + hi * 8);
#pragma unroll
        for (int s = 0; s < 5; ++s) { xc[2*s] = xrow[s*4]; xc[2*s+1] = xrow[s*4+1]; }
    }

    // W fragments, loaded once per wave (coalesced: lanes 0..31 read a 128B row)
    short8 Ws[5], Wd[5];
#pragma unroll
    for (int s = 0; s < 5; ++s) {
#pragma unroll
        for (int j = 0; j < 8; ++j) {
            int k = s * 16 + hi * 8 + j;
            Ws[s][j] = f2bf(W1[k * 32 + n]);
            Wd[s][j] = f2bf(W1[(81 + k) * 32 + n]);
        }
    }
    // C-init for PD: b1[feat] + W1[80][feat]
    float cdInit[16];
#pragma unroll
    for (int r = 0; r < 16; ++r) {
        int f = (r & 3) + 8 * (r >> 2) + 4 * hi;
        cdInit[r] = b1[f] + W1[80 * 32 + f];
    }

    while (tile < tiles) {
        const int nt = tile + stride;
        float4 xn[10];
        if (nt < tiles) {   // prefetch next tile's X under this tile's compute
            const float4* xrow = (const float4*)(X + (size_t)(nt * 32 + n) * D_NODE + hi * 8);
#pragma unroll
            for (int s = 0; s < 5; ++s) { xn[2*s] = xrow[s*4]; xn[2*s+1] = xrow[s*4+1]; }
        }

        f32x16 cs, cd;
#pragma unroll
        for (int r = 0; r < 16; ++r) { cs[r] = 0.0f; cd[r] = cdInit[r]; }

#pragma unroll
        for (int s = 0; s < 5; ++s) {
            union { uint4 u; short8 s8; } Bx;
            Bx.u.x = packbf2(xc[2*s].x, xc[2*s].y);
            Bx.u.y = packbf2(xc[2*s].z, xc[2*s].w);
            Bx.u.z = packbf2(xc[2*s+1].x, xc[2*s+1].y);
            Bx.u.w = packbf2(xc[2*s+1].z, xc[2*s+1].w);
            cs = __builtin_amdgcn_mfma_f32_32x32x16_bf16(Ws[s], Bx.s8, cs, 0, 0, 0);
            cd = __builtin_amdgcn_mfma_f32_32x32x16_bf16(Wd[s], Bx.s8, cd, 0, 0, 0);
        }

        const int node = tile * 32 + n;
        unsigned short* psr = PS + (size_t)node * 32 + hi * 4;
        unsigned short* pdr = PD + (size_t)node * 32 + hi * 4;
#pragma unroll
        for (int q = 0; q < 4; ++q) {
            uint2 vs = make_uint2(packbf2(cs[4*q+0], cs[4*q+1]),
                                  packbf2(cs[4*q+2], cs[4*q+3]));
            uint2 vd = make_uint2(packbf2(cd[4*q+0], cd[4*q+1]),
                                  packbf2(cd[4*q+2], cd[4*q+3]));
            *(uint2*)(psr + q * 8) = vs;
            *(uint2*)(pdr + q * 8) = vd;
        }

#pragma unroll
        for (int i = 0; i < 10; ++i) xc[i] = xn[i];
        tile = nt;
    }
}

// Kernel 2: 32 edges per wave-iteration via mfma_f32_32x32x16_bf16.
// EI=4 with ALL 16 row-gathers issued upfront and PINNED above the compute
// by sched_barrier(0) (round-6's unpinned version was sunk by the compiler).
__global__ __launch_bounds__(256) void edge_kernel(
    const int* __restrict__ ei,
    const unsigned short* __restrict__ PS, const unsigned short* __restrict__ PD,
    const float* __restrict__ W2, const float* __restrict__ b2,
    const float* __restrict__ W3, const float* __restrict__ b3,
    float* __restrict__ out, int E)
{
    const int tid  = threadIdx.x;
    const int wave = tid >> 6;
    const int lane = tid & 63;
    const int n    = lane & 31;   // edge-in-tile (B col / C col)
    const int hi   = lane >> 5;   // k-slot group

    const long base = ((long)blockIdx.x * 4 + wave) * (32 * EDGE_ITERS);

    // index loads first — in flight before anything else
    int sIdx[EDGE_ITERS], dIdx[EDGE_ITERS];
#pragma unroll
    for (int it = 0; it < EDGE_ITERS; ++it) {
        long e = base + (long)it * 32 + n;
        int ec = (e < E) ? (int)e : 0;
        sIdx[it] = ei[ec];
        dIdx[it] = ei[(size_t)E + ec];
    }

    // row gathers for ALL tiles issued upfront, pinned (16 x 16B per lane)
    uint4 av0[EDGE_ITERS], av1[EDGE_ITERS], bv0[EDGE_ITERS], bv1[EDGE_ITERS];
#pragma unroll
    for (int it = 0; it < EDGE_ITERS; ++it) {
        av0[it] = *(const uint4*)(PS + (size_t)sIdx[it] * 32 + hi * 8);
        av1[it] = *(const uint4*)(PS + (size_t)sIdx[it] * 32 + 16 + hi * 8);
        bv0[it] = *(const uint4*)(PD + (size_t)dIdx[it] * 32 + hi * 8);
        bv1[it] = *(const uint4*)(PD + (size_t)dIdx[it] * 32 + 16 + hi * 8);
    }
    __builtin_amdgcn_sched_barrier(0);   // forbid sinking the gathers below

    // A fragments: step t, slot j <-> k = t*16 + hi*8 + j; A[m=n][k] = W2[k][m]
    short8 Wa0, Wa1;
#pragma unroll
    for (int j = 0; j < 8; ++j) {
        int k0 = hi * 8 + j;
        Wa0[j] = f2bf(W2[k0 * 32 + n]);
        Wa1[j] = f2bf(W2[(16 + k0) * 32 + n]);
    }
    // per-lane constants for the 16 C-rows this lane owns (packed bf16 pairs)
    unsigned b2p[8], w3p[16];
#pragma unroll
    for (int r = 0; r < 16; ++r) {
        int row = (r & 3) + 8 * (r >> 2) + 4 * hi;
        w3p[r] = packbf2(W3[row * 2 + 0], W3[row * 2 + 1]);
        if ((r & 1) == 0) {
            int row2 = ((r + 1) & 3) + 8 * ((r + 1) >> 2) + 4 * hi;
            b2p[r >> 1] = packbf2(b2[row], b2[row2]);
        }
    }
    const float b30 = b3[0], b31 = b3[1];

#pragma unroll
    for (int it = 0; it < EDGE_ITERS; ++it) {
        union { uint4 u; short8 s8; } B0, B1;
        B0.u.x = packbf2(fmaxf(bf16lo(av0[it].x) + bf16lo(bv0[it].x), 0.f),
                         fmaxf(bf16hi(av0[it].x) + bf16hi(bv0[it].x), 0.f));
        B0.u.y = packbf2(fmaxf(bf16lo(av0[it].y) + bf16lo(bv0[it].y), 0.f),
                         fmaxf(bf16hi(av0[it].y) + bf16hi(bv0[it].y), 0.f));
        B0.u.z = packbf2(fmaxf(bf16lo(av0[it].z) + bf16lo(bv0[it].z), 0.f),
                         fmaxf(bf16hi(av0[it].z) + bf16hi(bv0[it].z), 0.f));
        B0.u.w = packbf2(fmaxf(bf16lo(av0[it].w) + bf16lo(bv0[it].w), 0.f),
                         fmaxf(bf16hi(av0[it].w) + bf16hi(bv0[it].w), 0.f));
        B1.u.x = packbf2(fmaxf(bf16lo(av1[it].x) + bf16lo(bv1[it].x), 0.f),
                         fmaxf(bf16hi(av1[it].x) + bf16hi(bv1[it].x), 0.f));
        B1.u.y = packbf2(fmaxf(bf16lo(av1[it].y) + bf16lo(bv1[it].y), 0.f),
                         fmaxf(bf16hi(av1[it].y) + bf16hi(bv1[it].y), 0.f));
        B1.u.z = packbf2(fmaxf(bf16lo(av1[it].z) + bf16lo(bv1[it].z), 0.f),
                         fmaxf(bf16hi(av1[it].z) + bf16hi(bv1[it].z), 0.f));
        B1.u.w = packbf2(fmaxf(bf16lo(av1[it].w) + bf16lo(bv1[it].w), 0.f),
                         fmaxf(bf16hi(av1[it].w) + bf16hi(bv1[it].w), 0.f));

        f32x16 c;
#pragma unroll
        for (int q = 0; q < 8; ++q) {
            c[2*q]   = bf16lo(b2p[q]);
            c[2*q+1] = bf16hi(b2p[q]);
        }
        c = __builtin_amdgcn_mfma_f32_32x32x16_bf16(Wa0, B0.s8, c, 0, 0, 0);
        c = __builtin_amdgcn_mfma_f32_32x32x16_bf16(Wa1, B1.s8, c, 0, 0, 0);

        float p0 = 0.f, p1 = 0.f;
#pragma unroll
        for (int r = 0; r < 16; ++r) {
            float h = fmaxf(c[r], 0.f);
            p0 += h * bf16lo(w3p[r]);
            p1 += h * bf16hi(w3p[r]);
        }
        p0 += __shfl_xor(p0, 32, 64);
        p1 += __shfl_xor(p1, 32, 64);

        if (hi == 0) {
            long eo = base + (long)it * 32 + n;
            if (eo < E) {
                float l0 = p0 + b30;
                float l1 = p1 + b31;
                float mm = fmaxf(l0, l1);
                float z  = __expf(l0 - mm) + __expf(l1 - mm);
                float lse = mm + __logf(z);
                *(float2*)(out + 2 * eo) = make_float2(l0 - lse, l1 - lse);
            }
        }
    }
}

extern "C" void kernel_launch(void* const* d_in, const int* in_sizes, int n_in,
                              void* d_out, int out_size, void* d_ws, size_t ws_size,
                              hipStream_t stream) {
    const float* X  = (const float*)d_in[0];
    const int*   ei = (const int*)d_in[1];
    const float* W1 = (const float*)d_in[2];
    const float* b1 = (const float*)d_in[3];
    const float* W2 = (const float*)d_in[4];
    const float* b2 = (const float*)d_in[5];
    const float* W3 = (const float*)d_in[6];
    const float* b3 = (const float*)d_in[7];
    float* out = (float*)d_out;

    int N = in_sizes[0] / D_NODE;   // 100000
    int E = in_sizes[1] / 2;        // 1600000

    unsigned short* PS = (unsigned short*)d_ws;            // N*32 bf16 = 6.4 MB
    unsigned short* PD = PS + (size_t)N * 32;              // N*32 bf16 = 6.4 MB

    proj_kernel<<<256, 256, 0, stream>>>(X, W1, b1, PS, PD, N);

    int edges_per_block = 4 * 32 * EDGE_ITERS;             // 512
    int nblk = (E + edges_per_block - 1) / edges_per_block; // 3125
    edge_kernel<<<nblk, 256, 0, stream>>>(ei, PS, PD, W2, b2, W3, b3, out, E);
}

// Round 10
// 62.105 us; speedup vs baseline: 1.2095x; 1.0355x over previous
//
#include <hip/hip_runtime.h>
#include <hip/hip_bf16.h>

#define D_NODE 80
#define EDGE_ITERS 2   // 32-edge tiles per wave; gathers issued upfront

typedef __attribute__((ext_vector_type(8))) short short8;
typedef __attribute__((ext_vector_type(16))) float f32x16;

__device__ __forceinline__ float bf16lo(unsigned u) {
    return __uint_as_float(u << 16);
}
__device__ __forceinline__ float bf16hi(unsigned u) {
    return __uint_as_float(u & 0xffff0000u);
}
__device__ __forceinline__ unsigned packbf2(float a, float b) {
    __hip_bfloat162 h = __float22bfloat162_rn(make_float2(a, b));
    union { __hip_bfloat162 h2; unsigned u; } cv; cv.h2 = h;
    return cv.u;   // low 16 bits = a, high = b
}
__device__ __forceinline__ short f2bf(float f) {
    __hip_bfloat16 h = __float2bfloat16(f);
    union { __hip_bfloat16 h1; short s; } cv; cv.h1 = h;
    return cv.s;
}

// Kernel 1: per-node projection as MFMA GEMM. ONE tile per wave, straight-line:
// X loads issued first, W-fragment setup overlaps the X latency, 10 MFMAs,
// store, exit. 782 blocks -> ~3 blocks/CU resident.
// cs = X @ W1[0:80] -> PS ; cd = X @ W1[81:161] + (b1 + W1[80]) -> PD.
// C/D layout: col = lane&31 (node), row(feat) = (r&3)+8*(r>>2)+4*(lane>>5).
__global__ __launch_bounds__(256) void proj_kernel(
    const float* __restrict__ X, const float* __restrict__ W1,
    const float* __restrict__ b1,
    unsigned short* __restrict__ PS, unsigned short* __restrict__ PD, int N)
{
    const int lane = threadIdx.x & 63;
    const int wave = threadIdx.x >> 6;
    const int n    = lane & 31;   // node-in-tile (B/C col) ; feat (A row) for W loads
    const int hi   = lane >> 5;   // k-slot group

    const int tiles = N / 32;                 // 3125 for N=100000
    const int tile  = blockIdx.x * 4 + wave;  // 782*4 = 3128 >= 3125
    const int t     = (tile < tiles) ? tile : 0;

    // X loads first — in flight while W fragments are fetched/converted
    float4 xc[10];
    {
        const float4* xrow = (const float4*)(X + (size_t)(t * 32 + n) * D_NODE + hi * 8);
#pragma unroll
        for (int s = 0; s < 5; ++s) { xc[2*s] = xrow[s*4]; xc[2*s+1] = xrow[s*4+1]; }
    }

    // W fragments (coalesced: lanes 0..31 read a 128B row; L2-resident after warmup)
    short8 Ws[5], Wd[5];
#pragma unroll
    for (int s = 0; s < 5; ++s) {
#pragma unroll
        for (int j = 0; j < 8; ++j) {
            int k = s * 16 + hi * 8 + j;
            Ws[s][j] = f2bf(W1[k * 32 + n]);
            Wd[s][j] = f2bf(W1[(81 + k) * 32 + n]);
        }
    }

    f32x16 cs, cd;
#pragma unroll
    for (int r = 0; r < 16; ++r) {
        int f = (r & 3) + 8 * (r >> 2) + 4 * hi;
        cs[r] = 0.0f;
        cd[r] = b1[f] + W1[80 * 32 + f];   // folded const-edge-feature row + bias
    }

#pragma unroll
    for (int s = 0; s < 5; ++s) {
        union { uint4 u; short8 s8; } Bx;
        Bx.u.x = packbf2(xc[2*s].x, xc[2*s].y);
        Bx.u.y = packbf2(xc[2*s].z, xc[2*s].w);
        Bx.u.z = packbf2(xc[2*s+1].x, xc[2*s+1].y);
        Bx.u.w = packbf2(xc[2*s+1].z, xc[2*s+1].w);
        cs = __builtin_amdgcn_mfma_f32_32x32x16_bf16(Ws[s], Bx.s8, cs, 0, 0, 0);
        cd = __builtin_amdgcn_mfma_f32_32x32x16_bf16(Wd[s], Bx.s8, cd, 0, 0, 0);
    }

    if (tile >= tiles) return;
    const int node = t * 32 + n;
    unsigned short* psr = PS + (size_t)node * 32 + hi * 4;
    unsigned short* pdr = PD + (size_t)node * 32 + hi * 4;
#pragma unroll
    for (int q = 0; q < 4; ++q) {
        uint2 vs = make_uint2(packbf2(cs[4*q+0], cs[4*q+1]),
                              packbf2(cs[4*q+2], cs[4*q+3]));
        uint2 vd = make_uint2(packbf2(cd[4*q+0], cd[4*q+1]),
                              packbf2(cd[4*q+2], cd[4*q+3]));
        *(uint2*)(psr + q * 8) = vs;
        *(uint2*)(pdr + q * 8) = vd;
    }
}

// Kernel 2: 32 edges per wave-iteration via mfma_f32_32x32x16_bf16.
// (byte-identical to round-7's edge kernel — best measured: 46.4 us,
//  EI=2, 8 gathers in flight, occ ~33%)
__global__ __launch_bounds__(256) void edge_kernel(
    const int* __restrict__ ei,
    const unsigned short* __restrict__ PS, const unsigned short* __restrict__ PD,
    const float* __restrict__ W2, const float* __restrict__ b2,
    const float* __restrict__ W3, const float* __restrict__ b3,
    float* __restrict__ out, int E)
{
    const int tid  = threadIdx.x;
    const int wave = tid >> 6;
    const int lane = tid & 63;
    const int n    = lane & 31;   // edge-in-tile (B col / C col)
    const int hi   = lane >> 5;   // k-slot group

    // A fragments: step t, slot j <-> k = t*16 + hi*8 + j; A[m=n][k] = W2[k][m]
    short8 Wa0, Wa1;
#pragma unroll
    for (int j = 0; j < 8; ++j) {
        int k0 = hi * 8 + j;
        Wa0[j] = f2bf(W2[k0 * 32 + n]);
        Wa1[j] = f2bf(W2[(16 + k0) * 32 + n]);
    }
    // per-lane constants for the 16 C-rows this lane owns (packed bf16 pairs)
    unsigned b2p[8], w3p[16];
#pragma unroll
    for (int r = 0; r < 16; ++r) {
        int row = (r & 3) + 8 * (r >> 2) + 4 * hi;
        w3p[r] = packbf2(W3[row * 2 + 0], W3[row * 2 + 1]);
        if ((r & 1) == 0) {
            int row2 = ((r + 1) & 3) + 8 * ((r + 1) >> 2) + 4 * hi;
            b2p[r >> 1] = packbf2(b2[row], b2[row2]);
        }
    }
    const float b30 = b3[0], b31 = b3[1];

    const long base = ((long)blockIdx.x * 4 + wave) * (32 * EDGE_ITERS);

    // index loads: all in flight immediately
    int sIdx[EDGE_ITERS], dIdx[EDGE_ITERS];
#pragma unroll
    for (int it = 0; it < EDGE_ITERS; ++it) {
        long e = base + (long)it * 32 + n;
        int ec = (e < E) ? (int)e : 0;
        sIdx[it] = ei[ec];
        dIdx[it] = ei[(size_t)E + ec];
    }

    // row gathers for BOTH tiles issued upfront (8 x 16B in flight per lane)
    uint4 av0[EDGE_ITERS], av1[EDGE_ITERS], bv0[EDGE_ITERS], bv1[EDGE_ITERS];
#pragma unroll
    for (int it = 0; it < EDGE_ITERS; ++it) {
        av0[it] = *(const uint4*)(PS + (size_t)sIdx[it] * 32 + hi * 8);
        av1[it] = *(const uint4*)(PS + (size_t)sIdx[it] * 32 + 16 + hi * 8);
        bv0[it] = *(const uint4*)(PD + (size_t)dIdx[it] * 32 + hi * 8);
        bv1[it] = *(const uint4*)(PD + (size_t)dIdx[it] * 32 + 16 + hi * 8);
    }

#pragma unroll
    for (int it = 0; it < EDGE_ITERS; ++it) {
        union { uint4 u; short8 s8; } B0, B1;
        B0.u.x = packbf2(fmaxf(bf16lo(av0[it].x) + bf16lo(bv0[it].x), 0.f),
                         fmaxf(bf16hi(av0[it].x) + bf16hi(bv0[it].x), 0.f));
        B0.u.y = packbf2(fmaxf(bf16lo(av0[it].y) + bf16lo(bv0[it].y), 0.f),
                         fmaxf(bf16hi(av0[it].y) + bf16hi(bv0[it].y), 0.f));
        B0.u.z = packbf2(fmaxf(bf16lo(av0[it].z) + bf16lo(bv0[it].z), 0.f),
                         fmaxf(bf16hi(av0[it].z) + bf16hi(bv0[it].z), 0.f));
        B0.u.w = packbf2(fmaxf(bf16lo(av0[it].w) + bf16lo(bv0[it].w), 0.f),
                         fmaxf(bf16hi(av0[it].w) + bf16hi(bv0[it].w), 0.f));
        B1.u.x = packbf2(fmaxf(bf16lo(av1[it].x) + bf16lo(bv1[it].x), 0.f),
                         fmaxf(bf16hi(av1[it].x) + bf16hi(bv1[it].x), 0.f));
        B1.u.y = packbf2(fmaxf(bf16lo(av1[it].y) + bf16lo(bv1[it].y), 0.f),
                         fmaxf(bf16hi(av1[it].y) + bf16hi(bv1[it].y), 0.f));
        B1.u.z = packbf2(fmaxf(bf16lo(av1[it].z) + bf16lo(bv1[it].z), 0.f),
                         fmaxf(bf16hi(av1[it].z) + bf16hi(bv1[it].z), 0.f));
        B1.u.w = packbf2(fmaxf(bf16lo(av1[it].w) + bf16lo(bv1[it].w), 0.f),
                         fmaxf(bf16hi(av1[it].w) + bf16hi(bv1[it].w), 0.f));

        f32x16 c;
#pragma unroll
        for (int q = 0; q < 8; ++q) {
            c[2*q]   = bf16lo(b2p[q]);
            c[2*q+1] = bf16hi(b2p[q]);
        }
        c = __builtin_amdgcn_mfma_f32_32x32x16_bf16(Wa0, B0.s8, c, 0, 0, 0);
        c = __builtin_amdgcn_mfma_f32_32x32x16_bf16(Wa1, B1.s8, c, 0, 0, 0);

        float p0 = 0.f, p1 = 0.f;
#pragma unroll
        for (int r = 0; r < 16; ++r) {
            float h = fmaxf(c[r], 0.f);
            p0 += h * bf16lo(w3p[r]);
            p1 += h * bf16hi(w3p[r]);
        }
        p0 += __shfl_xor(p0, 32, 64);
        p1 += __shfl_xor(p1, 32, 64);

        if (hi == 0) {
            long eo = base + (long)it * 32 + n;
            if (eo < E) {
                float l0 = p0 + b30;
                float l1 = p1 + b31;
                float mm = fmaxf(l0, l1);
                float z  = __expf(l0 - mm) + __expf(l1 - mm);
                float lse = mm + __logf(z);
                *(float2*)(out + 2 * eo) = make_float2(l0 - lse, l1 - lse);
            }
        }
    }
}

extern "C" void kernel_launch(void* const* d_in, const int* in_sizes, int n_in,
                              void* d_out, int out_size, void* d_ws, size_t ws_size,
                              hipStream_t stream) {
    const float* X  = (const float*)d_in[0];
    const int*   ei = (const int*)d_in[1];
    const float* W1 = (const float*)d_in[2];
    const float* b1 = (const float*)d_in[3];
    const float* W2 = (const float*)d_in[4];
    const float* b2 = (const float*)d_in[5];
    const float* W3 = (const float*)d_in[6];
    const float* b3 = (const float*)d_in[7];
    float* out = (float*)d_out;

    int N = in_sizes[0] / D_NODE;   // 100000
    int E = in_sizes[1] / 2;        // 1600000

    unsigned short* PS = (unsigned short*)d_ws;            // N*32 bf16 = 6.4 MB
    unsigned short* PD = PS + (size_t)N * 32;              // N*32 bf16 = 6.4 MB

    int pblk = (N / 32 + 3) / 4;                           // 782 blocks, 1 tile/wave
    proj_kernel<<<pblk, 256, 0, stream>>>(X, W1, b1, PS, PD, N);

    int edges_per_block = 4 * 32 * EDGE_ITERS;             // 256
    int nblk = (E + edges_per_block - 1) / edges_per_block; // 6250
    edge_kernel<<<nblk, 256, 0, stream>>>(ei, PS, PD, W2, b2, W3, b3, out, E);
}

// Round 11
// 61.560 us; speedup vs baseline: 1.2202x; 1.0088x over previous
//
#include <hip/hip_runtime.h>
#include <hip/hip_bf16.h>

#define D_NODE 80
#define EDGE_ITERS 2   // 32-edge tiles per wave; gathers issued upfront

typedef __attribute__((ext_vector_type(8))) short short8;
typedef __attribute__((ext_vector_type(16))) float f32x16;

__device__ __forceinline__ float bf16lo(unsigned u) {
    return __uint_as_float(u << 16);
}
__device__ __forceinline__ float bf16hi(unsigned u) {
    return __uint_as_float(u & 0xffff0000u);
}
__device__ __forceinline__ unsigned packbf2(float a, float b) {
    __hip_bfloat162 h = __float22bfloat162_rn(make_float2(a, b));
    union { __hip_bfloat162 h2; unsigned u; } cv; cv.h2 = h;
    return cv.u;   // low 16 bits = a, high = b
}
__device__ __forceinline__ short f2bf(float f) {
    __hip_bfloat16 h = __float2bfloat16(f);
    union { __hip_bfloat16 h1; short s; } cv; cv.h1 = h;
    return cv.s;
}

#define XSTRIDE 96   // bf16 elems; 192 B row stride -> 2-way LDS bank alias (free), 16B-aligned

// Kernel 1: per-node projection as MFMA GEMM with COALESCED X staging.
// Each wave: 10 lane-major float4 wave-loads (1 KB coalesced each) of its
// 32x80 f32 X tile -> bf16 -> LDS (padded stride 96) -> ds_read_b128 gives
// each lane its short8 B-fragment directly. Kills the 320B-stride divergent
// global loads (640 txns/tile -> 80) that pinned proj at ~16 us.
__global__ __launch_bounds__(256) void proj_kernel(
    const float* __restrict__ X, const float* __restrict__ W1,
    const float* __restrict__ b1,
    unsigned short* __restrict__ PS, unsigned short* __restrict__ PD, int N)
{
    __shared__ unsigned short sX[4][32 * XSTRIDE];   // 24.6 KB

    const int lane = threadIdx.x & 63;
    const int wave = threadIdx.x >> 6;
    const int n    = lane & 31;   // node-in-tile (B/C col) ; feat (A row) for W loads
    const int hi   = lane >> 5;   // k-slot group

    const int tiles = N / 32;                 // 3125 for N=100000
    const int tile  = blockIdx.x * 4 + wave;  // 782*4 = 3128 >= 3125
    const int t     = (tile < tiles) ? tile : 0;

    // coalesced X load: tile block = 2560 floats = 640 float4; 10 per lane
    float4 xl[10];
    {
        const float4* xbase = (const float4*)(X + (size_t)t * 32 * D_NODE);
#pragma unroll
        for (int i = 0; i < 10; ++i) xl[i] = xbase[lane + i * 64];
    }

    // W fragments (coalesced; L2-resident after warmup) — overlaps X latency
    short8 Ws[5], Wd[5];
#pragma unroll
    for (int s = 0; s < 5; ++s) {
#pragma unroll
        for (int j = 0; j < 8; ++j) {
            int k = s * 16 + hi * 8 + j;
            Ws[s][j] = f2bf(W1[k * 32 + n]);
            Wd[s][j] = f2bf(W1[(81 + k) * 32 + n]);
        }
    }

    // stage X tile to LDS as bf16 (padded row stride)
    unsigned short* sx = sX[wave];
#pragma unroll
    for (int i = 0; i < 10; ++i) {
        int e   = (lane + i * 64) * 4;    // first f32 elem idx in tile (mult of 4)
        int row = e / D_NODE;
        int col = e - row * D_NODE;       // 4 floats never cross a row (4 | 80)
        uint2 v = make_uint2(packbf2(xl[i].x, xl[i].y),
                             packbf2(xl[i].z, xl[i].w));
        *(uint2*)(sx + row * XSTRIDE + col) = v;
    }
    __syncthreads();

    f32x16 cs, cd;
#pragma unroll
    for (int r = 0; r < 16; ++r) {
        int f = (r & 3) + 8 * (r >> 2) + 4 * hi;
        cs[r] = 0.0f;
        cd[r] = b1[f] + W1[80 * 32 + f];   // folded const-edge-feature row + bias
    }

#pragma unroll
    for (int s = 0; s < 5; ++s) {
        short8 Bx = *(const short8*)(sx + n * XSTRIDE + s * 16 + hi * 8);
        cs = __builtin_amdgcn_mfma_f32_32x32x16_bf16(Ws[s], Bx, cs, 0, 0, 0);
        cd = __builtin_amdgcn_mfma_f32_32x32x16_bf16(Wd[s], Bx, cd, 0, 0, 0);
    }

    if (tile >= tiles) return;
    const int node = t * 32 + n;
    unsigned short* psr = PS + (size_t)node * 32 + hi * 4;
    unsigned short* pdr = PD + (size_t)node * 32 + hi * 4;
#pragma unroll
    for (int q = 0; q < 4; ++q) {
        uint2 vs = make_uint2(packbf2(cs[4*q+0], cs[4*q+1]),
                              packbf2(cs[4*q+2], cs[4*q+3]));
        uint2 vd = make_uint2(packbf2(cd[4*q+0], cd[4*q+1]),
                              packbf2(cd[4*q+2], cd[4*q+3]));
        *(uint2*)(psr + q * 8) = vs;
        *(uint2*)(pdr + q * 8) = vd;
    }
}

// Kernel 2: 32 edges per wave-iteration via mfma_f32_32x32x16_bf16.
// (byte-identical to round-7/10 edge kernel — best measured: 45.5-46.4 us)
__global__ __launch_bounds__(256) void edge_kernel(
    const int* __restrict__ ei,
    const unsigned short* __restrict__ PS, const unsigned short* __restrict__ PD,
    const float* __restrict__ W2, const float* __restrict__ b2,
    const float* __restrict__ W3, const float* __restrict__ b3,
    float* __restrict__ out, int E)
{
    const int tid  = threadIdx.x;
    const int wave = tid >> 6;
    const int lane = tid & 63;
    const int n    = lane & 31;   // edge-in-tile (B col / C col)
    const int hi   = lane >> 5;   // k-slot group

    // A fragments: step t, slot j <-> k = t*16 + hi*8 + j; A[m=n][k] = W2[k][m]
    short8 Wa0, Wa1;
#pragma unroll
    for (int j = 0; j < 8; ++j) {
        int k0 = hi * 8 + j;
        Wa0[j] = f2bf(W2[k0 * 32 + n]);
        Wa1[j] = f2bf(W2[(16 + k0) * 32 + n]);
    }
    // per-lane constants for the 16 C-rows this lane owns (packed bf16 pairs)
    unsigned b2p[8], w3p[16];
#pragma unroll
    for (int r = 0; r < 16; ++r) {
        int row = (r & 3) + 8 * (r >> 2) + 4 * hi;
        w3p[r] = packbf2(W3[row * 2 + 0], W3[row * 2 + 1]);
        if ((r & 1) == 0) {
            int row2 = ((r + 1) & 3) + 8 * ((r + 1) >> 2) + 4 * hi;
            b2p[r >> 1] = packbf2(b2[row], b2[row2]);
        }
    }
    const float b30 = b3[0], b31 = b3[1];

    const long base = ((long)blockIdx.x * 4 + wave) * (32 * EDGE_ITERS);

    // index loads: all in flight immediately
    int sIdx[EDGE_ITERS], dIdx[EDGE_ITERS];
#pragma unroll
    for (int it = 0; it < EDGE_ITERS; ++it) {
        long e = base + (long)it * 32 + n;
        int ec = (e < E) ? (int)e : 0;
        sIdx[it] = ei[ec];
        dIdx[it] = ei[(size_t)E + ec];
    }

    // row gathers for BOTH tiles issued upfront (8 x 16B in flight per lane)
    uint4 av0[EDGE_ITERS], av1[EDGE_ITERS], bv0[EDGE_ITERS], bv1[EDGE_ITERS];
#pragma unroll
    for (int it = 0; it < EDGE_ITERS; ++it) {
        av0[it] = *(const uint4*)(PS + (size_t)sIdx[it] * 32 + hi * 8);
        av1[it] = *(const uint4*)(PS + (size_t)sIdx[it] * 32 + 16 + hi * 8);
        bv0[it] = *(const uint4*)(PD + (size_t)dIdx[it] * 32 + hi * 8);
        bv1[it] = *(const uint4*)(PD + (size_t)dIdx[it] * 32 + 16 + hi * 8);
    }

#pragma unroll
    for (int it = 0; it < EDGE_ITERS; ++it) {
        union { uint4 u; short8 s8; } B0, B1;
        B0.u.x = packbf2(fmaxf(bf16lo(av0[it].x) + bf16lo(bv0[it].x), 0.f),
                         fmaxf(bf16hi(av0[it].x) + bf16hi(bv0[it].x), 0.f));
        B0.u.y = packbf2(fmaxf(bf16lo(av0[it].y) + bf16lo(bv0[it].y), 0.f),
                         fmaxf(bf16hi(av0[it].y) + bf16hi(bv0[it].y), 0.f));
        B0.u.z = packbf2(fmaxf(bf16lo(av0[it].z) + bf16lo(bv0[it].z), 0.f),
                         fmaxf(bf16hi(av0[it].z) + bf16hi(bv0[it].z), 0.f));
        B0.u.w = packbf2(fmaxf(bf16lo(av0[it].w) + bf16lo(bv0[it].w), 0.f),
                         fmaxf(bf16hi(av0[it].w) + bf16hi(bv0[it].w), 0.f));
        B1.u.x = packbf2(fmaxf(bf16lo(av1[it].x) + bf16lo(bv1[it].x), 0.f),
                         fmaxf(bf16hi(av1[it].x) + bf16hi(bv1[it].x), 0.f));
        B1.u.y = packbf2(fmaxf(bf16lo(av1[it].y) + bf16lo(bv1[it].y), 0.f),
                         fmaxf(bf16hi(av1[it].y) + bf16hi(bv1[it].y), 0.f));
        B1.u.z = packbf2(fmaxf(bf16lo(av1[it].z) + bf16lo(bv1[it].z), 0.f),
                         fmaxf(bf16hi(av1[it].z) + bf16hi(bv1[it].z), 0.f));
        B1.u.w = packbf2(fmaxf(bf16lo(av1[it].w) + bf16lo(bv1[it].w), 0.f),
                         fmaxf(bf16hi(av1[it].w) + bf16hi(bv1[it].w), 0.f));

        f32x16 c;
#pragma unroll
        for (int q = 0; q < 8; ++q) {
            c[2*q]   = bf16lo(b2p[q]);
            c[2*q+1] = bf16hi(b2p[q]);
        }
        c = __builtin_amdgcn_mfma_f32_32x32x16_bf16(Wa0, B0.s8, c, 0, 0, 0);
        c = __builtin_amdgcn_mfma_f32_32x32x16_bf16(Wa1, B1.s8, c, 0, 0, 0);

        float p0 = 0.f, p1 = 0.f;
#pragma unroll
        for (int r = 0; r < 16; ++r) {
            float h = fmaxf(c[r], 0.f);
            p0 += h * bf16lo(w3p[r]);
            p1 += h * bf16hi(w3p[r]);
        }
        p0 += __shfl_xor(p0, 32, 64);
        p1 += __shfl_xor(p1, 32, 64);

        if (hi == 0) {
            long eo = base + (long)it * 32 + n;
            if (eo < E) {
                float l0 = p0 + b30;
                float l1 = p1 + b31;
                float mm = fmaxf(l0, l1);
                float z  = __expf(l0 - mm) + __expf(l1 - mm);
                float lse = mm + __logf(z);
                *(float2*)(out + 2 * eo) = make_float2(l0 - lse, l1 - lse);
            }
        }
    }
}

extern "C" void kernel_launch(void* const* d_in, const int* in_sizes, int n_in,
                              void* d_out, int out_size, void* d_ws, size_t ws_size,
                              hipStream_t stream) {
    const float* X  = (const float*)d_in[0];
    const int*   ei = (const int*)d_in[1];
    const float* W1 = (const float*)d_in[2];
    const float* b1 = (const float*)d_in[3];
    const float* W2 = (const float*)d_in[4];
    const float* b2 = (const float*)d_in[5];
    const float* W3 = (const float*)d_in[6];
    const float* b3 = (const float*)d_in[7];
    float* out = (float*)d_out;

    int N = in_sizes[0] / D_NODE;   // 100000
    int E = in_sizes[1] / 2;        // 1600000

    unsigned short* PS = (unsigned short*)d_ws;            // N*32 bf16 = 6.4 MB
    unsigned short* PD = PS + (size_t)N * 32;              // N*32 bf16 = 6.4 MB

    int pblk = (N / 32 + 3) / 4;                           // 782 blocks, 1 tile/wave
    proj_kernel<<<pblk, 256, 0, stream>>>(X, W1, b1, PS, PD, N);

    int edges_per_block = 4 * 32 * EDGE_ITERS;             // 256
    int nblk = (E + edges_per_block - 1) / edges_per_block; // 6250
    edge_kernel<<<nblk, 256, 0, stream>>>(ei, PS, PD, W2, b2, W3, b3, out, E);
}